// Round 15
// baseline (449.480 us; speedup 1.0000x reference)
//
#include <hip/hip_runtime.h>
#include <cstdint>
#include <cstddef>

// AttnBlock: B=4, C=512, H=W=64 (N=4096). All-fp32 I/O, bf16 MFMA internally.
// R15: R12 base (256x256/BK=64, 16 free-running 64x64 waves) but the B
//      operand bypasses LDS: per-wave register loads straight from L2/L3,
//      software-pipelined (bgA(t+1) issued after kh0, bgB(t+1) after kh1).
//      LDS traffic/tile halves (the measured bottleneck); B rides the idle
//      VMEM pipe. A staging/swizzle unchanged; counted vmcnt ledger for A.

#define CDIM 512
#define NSP  4096
#define NB   4
#define M0   12.0f

using bf16x8 = __attribute__((ext_vector_type(8))) __bf16;
using f32x4  = __attribute__((ext_vector_type(4))) float;
using u16x4  = __attribute__((ext_vector_type(4))) unsigned short;
using h8     = __attribute__((ext_vector_type(8))) _Float16;

__device__ __forceinline__ unsigned short f2bf(float f) {
  unsigned int u = __float_as_uint(f);
  u += 0x7fffu + ((u >> 16) & 1u);
  return (unsigned short)(u >> 16);
}

__device__ __forceinline__ void async_copy16(const unsigned short* g, unsigned short* l) {
  __builtin_amdgcn_global_load_lds(
      (const __attribute__((address_space(1))) void*)g,
      (__attribute__((address_space(3))) void*)l, 16, 0, 0);
}

// ---------------- GroupNorm stats: one block per (b, group) ----------------
__global__ __launch_bounds__(256) void gn_stats(const float* __restrict__ x,
                                                float* __restrict__ stats) {
  const size_t base = (size_t)blockIdx.x * 65536;  // 16 ch * 4096, contiguous
  const float4* p = (const float4*)(x + base);
  float s = 0.f, ss = 0.f;
  for (int i = threadIdx.x; i < 16384; i += 256) {
    float4 v = p[i];
    s  += v.x + v.y + v.z + v.w;
    ss += v.x*v.x + v.y*v.y + v.z*v.z + v.w*v.w;
  }
  for (int off = 32; off; off >>= 1) {
    s  += __shfl_xor(s, off);
    ss += __shfl_xor(ss, off);
  }
  __shared__ float rs[4], rss[4];
  const int w = threadIdx.x >> 6;
  if ((threadIdx.x & 63) == 0) { rs[w] = s; rss[w] = ss; }
  __syncthreads();
  if (threadIdx.x == 0) {
    float S  = rs[0] + rs[1] + rs[2] + rs[3];
    float SS = rss[0] + rss[1] + rss[2] + rss[3];
    float mean = S * (1.f / 65536.f);
    float var  = SS * (1.f / 65536.f) - mean * mean;
    stats[2 * blockIdx.x]     = mean;
    stats[2 * blockIdx.x + 1] = rsqrtf(var + 1e-6f);
  }
}

// ------------- normalize + transpose: x(B,C,N) f32 -> Hnt(B,N,C) bf16 -------
__global__ __launch_bounds__(256) void norm_transpose(
    const float* __restrict__ x, const float* __restrict__ stats,
    const float* __restrict__ gns, const float* __restrict__ gnb,
    unsigned short* __restrict__ hnt) {
  __shared__ float tile[64][65];
  const int b  = blockIdx.z;
  const int c0 = blockIdx.y * 64, n0 = blockIdx.x * 64;
  const int tx = threadIdx.x & 63, ty = threadIdx.x >> 6;
  for (int i = 0; i < 16; ++i) {
    int cl = ty * 16 + i;
    int c  = c0 + cl;
    int g  = c >> 4;
    float mean = stats[(b * 32 + g) * 2];
    float rstd = stats[(b * 32 + g) * 2 + 1];
    float v = x[((size_t)(b * CDIM + c)) * NSP + n0 + tx];
    tile[cl][tx] = (v - mean) * rstd * gns[c] + gnb[c];
  }
  __syncthreads();
  for (int i = 0; i < 16; ++i) {
    int nl = ty * 16 + i;
    hnt[((size_t)(b * NSP + n0 + nl)) * CDIM + c0 + tx] = f2bf(tile[tx][nl]);
  }
}

// ---------------- fp32 -> bf16 weight conversion (4 weights, one launch) ----
__global__ __launch_bounds__(256) void weights_to_bf16(
    const float* __restrict__ w0, const float* __restrict__ w1,
    const float* __restrict__ w2, const float* __restrict__ w3,
    unsigned short* __restrict__ o0, unsigned short* __restrict__ o1,
    unsigned short* __restrict__ o2, unsigned short* __restrict__ o3) {
  const float* s; unsigned short* o;
  switch (blockIdx.y) {
    case 0: s = w0; o = o0; break;
    case 1: s = w1; o = o1; break;
    case 2: s = w2; o = o2; break;
    default: s = w3; o = o3; break;
  }
  int i = blockIdx.x * 256 + threadIdx.x;
  float4 v = ((const float4*)s)[i];
  u16x4 r = {f2bf(v.x), f2bf(v.y), f2bf(v.z), f2bf(v.w)};
  *(u16x4*)(o + (size_t)i * 4) = r;
}

// ---------------- NT GEMM 128x128 (R4-proven, small projections) ----------
// FUSEQK: blockIdx.z = sel*4 + b; sel picks (Bt,Dv,bias) vs (Bt2,Dv2,bias2).
template <int BIAS_MODE, int OUT_MODE, int RESID, int FUSEQK>
__global__ __launch_bounds__(256) void gemm_nt(
    const unsigned short* __restrict__ A, const unsigned short* __restrict__ Bt,
    void* __restrict__ Dv, const float* __restrict__ bias,
    const float* __restrict__ resid,
    const unsigned short* __restrict__ Bt2, void* __restrict__ Dv2,
    const float* __restrict__ bias2,
    int M, int N, int K, float scale, long sA, long sB, long sD, long sR) {
  __shared__ unsigned short lsA[2][128 * 32];
  __shared__ unsigned short lsB[2][128 * 32];
  const int tid = threadIdx.x;
  const int w = tid >> 6, lane = tid & 63;
  const int wr = w >> 1, wc = w & 1;
  const int b = FUSEQK ? (blockIdx.z & 3) : blockIdx.z;
  if (FUSEQK && (blockIdx.z >> 2)) { Bt = Bt2; Dv = Dv2; bias = bias2; }
  const int bm0 = blockIdx.y * 128, bn0 = blockIdx.x * 128;
  const unsigned short* Ab = A + (size_t)b * sA;
  const unsigned short* Bb = Bt + (size_t)b * sB;

  f32x4 acc[4][4] = {};
  const int r0  = w * 16 + (lane >> 2);
  const int kof = (lane & 3) * 8;
  const int fr  = lane & 15, kf = (lane >> 4) * 8;

  for (int it = 0; it < 2; ++it) {
    int row = it * 64 + r0;
    async_copy16(Ab + (size_t)(bm0 + row) * K + kof, &lsA[0][row * 32 + kof]);
    async_copy16(Bb + (size_t)(bn0 + row) * K + kof, &lsB[0][row * 32 + kof]);
  }
  __syncthreads();

  int cur = 0;
  for (int k0 = 0; k0 < K; k0 += 32) {
    const int nk = k0 + 32;
    if (nk < K) {
      for (int it = 0; it < 2; ++it) {
        int row = it * 64 + r0;
        async_copy16(Ab + (size_t)(bm0 + row) * K + nk + kof, &lsA[cur ^ 1][row * 32 + kof]);
        async_copy16(Bb + (size_t)(bn0 + row) * K + nk + kof, &lsB[cur ^ 1][row * 32 + kof]);
      }
    }
    bf16x8 af[4], bff[4];
    for (int i = 0; i < 4; ++i) {
      af[i]  = *(const bf16x8*)(&lsA[cur][(wr * 64 + i * 16 + fr) * 32 + kf]);
      bff[i] = *(const bf16x8*)(&lsB[cur][(wc * 64 + i * 16 + fr) * 32 + kf]);
    }
    for (int i = 0; i < 4; ++i)
      for (int j = 0; j < 4; ++j)
        acc[i][j] = __builtin_amdgcn_mfma_f32_16x16x32_bf16(af[i], bff[j], acc[i][j], 0, 0, 0);
    __syncthreads();
    cur ^= 1;
  }

  const int col_l = lane & 15, row_l = (lane >> 4) * 4;
  for (int i = 0; i < 4; ++i)
    for (int j = 0; j < 4; ++j) {
      int gr = bm0 + wr * 64 + i * 16 + row_l;
      int gc = bn0 + wc * 64 + j * 16 + col_l;
      for (int r = 0; r < 4; ++r) {
        float v = acc[i][j][r] * scale;
        if (BIAS_MODE == 1) v += bias[gr + r];
        if (BIAS_MODE == 2) v += bias[gc];
        if (RESID) v += resid[(size_t)b * sR + (size_t)(gr + r) * N + gc];
        if (OUT_MODE == 1)
          ((unsigned short*)Dv)[(size_t)b * sD + (size_t)(gr + r) * N + gc] = f2bf(v);
        else
          ((float*)Dv)[(size_t)b * sD + (size_t)(gr + r) * N + gc] = v;
      }
    }
}

// ------- NT GEMM 256x256, BK=64, 16 free-running waves, B from global -------
// D[M,N] = A[M,K] @ Bt[N,K]^T. OUT_MODE: 1 bf16, 2 fp16.
// SPLITK: z = split*NB+b; EXPL: exp(acc*scale - M0) + lsum atomics.
// A: staged in LDS (swizzled source, linear dest) as R12. B: per-wave
// register loads direct from global (panels are L2/L3-resident), pipelined:
//   prologue: stageA(0), bgA(0), bgB(0)
//   tile t: stageA(t+1) -> vmcnt(6|4) [retires Ast(t)+bgA(t)] -> barrier ->
//           kh0 MFMA(bgA) -> issue bgA(t+1) ->
//           kh1 MFMA(bgB) [compiler-inserted vmcnt covers bgB] ->
//           issue bgB(t+1) -> barrier.
// LDS/tile: 128 KB reads + 64 KB writes (was 256+128) — the measured limit.
template <int OUT_MODE, int SPLITK, int EXPL>
__global__ __launch_bounds__(1024, 4) void gemm256wb(
    const unsigned short* __restrict__ A, const unsigned short* __restrict__ Bt,
    void* __restrict__ Dv, float* __restrict__ lsum,
    int M, int N, int K, float scale, long sA, long sB, long sD, int kLen) {
  __shared__ unsigned short lsA[2][256 * 64];   // 64 KB total
  const int tid = threadIdx.x;
  const int wid = tid >> 6, lane = tid & 63;
  const int wm = wid >> 2, wn = wid & 3;        // 4 x 4 wave grid, 64x64 each
  const int fr = lane & 15, kq = lane >> 4;
  const int b = SPLITK ? (blockIdx.z & 3) : blockIdx.z;
  const int bm0 = blockIdx.y * 256, bn0 = blockIdx.x * 256;
  const unsigned short* Ab = A + (size_t)b * sA;
  const unsigned short* Bb = Bt + (size_t)b * sB;
  const size_t dOff = SPLITK ? (size_t)blockIdx.z * (size_t)M * N
                             : (size_t)b * (size_t)sD;
  const int kStart = SPLITK ? (blockIdx.z >> 2) * kLen : 0;
  const int ntiles = (SPLITK ? kLen : K) >> 6;

  // stage A K-tile t (256 rows x 64 k) into buf: 2 loads/thread.
  auto stageA = [&](int t, int buf) {
    const int k0 = kStart + t * 64;
#pragma unroll
    for (int i = 0; i < 2; ++i) {
      const int idx = i * 1024 + tid;           // 256 rows x 8 chunks
      const int row = idx >> 3, ch = idx & 7;
      const int sch = ch ^ (row & 7);
      async_copy16(Ab + (size_t)(bm0 + row) * K + k0 + sch * 8,
                   &lsA[buf][row * 64 + ch * 8]);
    }
  };

  // B fragment base for this lane: row = bn0 + wn*64 + j*16 + fr, chunk kq.
  const unsigned short* Bl = Bb + (size_t)(bn0 + wn * 64 + fr) * K + kq * 8;
  bf16x8 bgA[4], bgB[4];   // kh=0 / kh=1 fragments, register-resident
#define LOADB(dst, t, kh)                                                     \
  {                                                                           \
    const int k0_ = kStart + (t) * 64 + (kh) * 32;                            \
    _Pragma("unroll")                                                         \
    for (int j = 0; j < 4; ++j)                                               \
      dst[j] = *(const bf16x8*)(Bl + (size_t)(j * 16) * K + k0_);             \
  }

  f32x4 acc[4][4] = {};
  const int arow = wm * 64 + fr;

  // prologue
  stageA(0, 0);
  LOADB(bgA, 0, 0)
  LOADB(bgB, 0, 1)

  for (int t = 0; t < ntiles; ++t) {
    const int cur = t & 1;
    const bool pre = (t + 1 < ntiles);
    if (pre) {
      stageA(t + 1, cur ^ 1);
      // outstanding: Ast(t)2, bgA(t)4, bgB(t)4, Ast(t+1)2 -> retire first 6
      asm volatile("s_waitcnt vmcnt(6)\n\ts_barrier" ::: "memory");
    } else {
      // outstanding: Ast(t)2, bgA(t)4, bgB(t)4 -> retire Ast+bgA
      asm volatile("s_waitcnt vmcnt(4)\n\ts_barrier" ::: "memory");
    }
    const unsigned short* la = &lsA[cur][0];

    // ---- kh = 0: consume bgA ----
    {
      const int cko = ((0 * 4 + kq) ^ (fr & 7)) * 8;
      bf16x8 af[4];
#pragma unroll
      for (int i = 0; i < 4; ++i)
        af[i] = *(const bf16x8*)&la[(arow + i * 16) * 64 + cko];
#pragma unroll
      for (int i = 0; i < 4; ++i)
#pragma unroll
        for (int j = 0; j < 4; ++j)
          acc[i][j] = __builtin_amdgcn_mfma_f32_16x16x32_bf16(af[i], bgA[j], acc[i][j], 0, 0, 0);
    }
    if (pre) LOADB(bgA, t + 1, 0)   // dest regs free; hidden under kh1+barrier

    // ---- kh = 1: consume bgB (compiler inserts its own vmcnt for bgB) ----
    {
      const int cko = ((1 * 4 + kq) ^ (fr & 7)) * 8;
      bf16x8 af[4];
#pragma unroll
      for (int i = 0; i < 4; ++i)
        af[i] = *(const bf16x8*)&la[(arow + i * 16) * 64 + cko];
#pragma unroll
      for (int i = 0; i < 4; ++i)
#pragma unroll
        for (int j = 0; j < 4; ++j)
          acc[i][j] = __builtin_amdgcn_mfma_f32_16x16x32_bf16(af[i], bgB[j], acc[i][j], 0, 0, 0);
    }
    if (pre) LOADB(bgB, t + 1, 1)

    asm volatile("s_barrier" ::: "memory");
  }
#undef LOADB

  // epilogue
  float rs[4][4];
  if (EXPL)
#pragma unroll
    for (int i = 0; i < 4; ++i)
#pragma unroll
      for (int r = 0; r < 4; ++r) rs[i][r] = 0.f;

#pragma unroll
  for (int mi = 0; mi < 4; ++mi)
#pragma unroll
    for (int ni = 0; ni < 4; ++ni) {
      const int gr = bm0 + wm * 64 + mi * 16 + kq * 4;
      const int gc = bn0 + wn * 64 + ni * 16 + fr;
#pragma unroll
      for (int r = 0; r < 4; ++r) {
        float v;
        if (EXPL) {
          v = __expf(fmaf(acc[mi][ni][r], scale, -M0));
          rs[mi][r] += v;
        } else {
          v = acc[mi][ni][r] * scale;
        }
        if (OUT_MODE == 1)
          ((unsigned short*)Dv)[dOff + (size_t)(gr + r) * N + gc] = f2bf(v);
        else
          ((_Float16*)Dv)[dOff + (size_t)(gr + r) * N + gc] = (_Float16)v;
      }
    }

  if (EXPL) {
#pragma unroll
    for (int mi = 0; mi < 4; ++mi)
#pragma unroll
      for (int r = 0; r < 4; ++r) {
        float v = rs[mi][r];
        v += __shfl_xor(v, 1); v += __shfl_xor(v, 2);
        v += __shfl_xor(v, 4); v += __shfl_xor(v, 8);
        if (fr == 0) {
          int gr = bm0 + wm * 64 + mi * 16 + kq * 4 + r;
          atomicAdd(&lsum[(size_t)b * M + gr], v);
        }
      }
  }
}

// ---------------- reduce: ot = (Op0 + Op1) / l  -> bf16 ----------------
__global__ __launch_bounds__(256) void reduce_div(const _Float16* __restrict__ Op,
                                                  const float* __restrict__ l,
                                                  unsigned short* __restrict__ ot) {
  const size_t stride = (size_t)NB * NSP * CDIM;  // elems per split
  size_t base = ((size_t)blockIdx.x * 256 + threadIdx.x) * 8;
  float linv = 1.f / l[base >> 9];  // row = base / 512
  h8 a = *(const h8*)(Op + base);
  h8 c = *(const h8*)(Op + stride + base);
  u16x4 o0, o1;
#pragma unroll
  for (int i = 0; i < 4; ++i) {
    o0[i] = f2bf(((float)a[i] + (float)c[i]) * linv);
    o1[i] = f2bf(((float)a[i + 4] + (float)c[i + 4]) * linv);
  }
  *(u16x4*)(ot + base) = o0;
  *(u16x4*)(ot + base + 4) = o1;
}

extern "C" void kernel_launch(void* const* d_in, const int* in_sizes, int n_in,
                              void* d_out, int out_size, void* d_ws, size_t ws_size,
                              hipStream_t stream) {
  const float* hs  = (const float*)d_in[0];
  const float* gns = (const float*)d_in[1];
  const float* gnb = (const float*)d_in[2];
  const float* wq  = (const float*)d_in[3];
  const float* bq  = (const float*)d_in[4];
  const float* wk  = (const float*)d_in[5];
  const float* bk  = (const float*)d_in[6];
  const float* wv  = (const float*)d_in[7];
  const float* bv  = (const float*)d_in[8];
  const float* wp  = (const float*)d_in[9];
  const float* bp  = (const float*)d_in[10];

  char* p = (char*)d_ws;
  unsigned short* wqb = (unsigned short*)p; p += (size_t)CDIM * CDIM * 2;
  unsigned short* wkb = (unsigned short*)p; p += (size_t)CDIM * CDIM * 2;
  unsigned short* wvb = (unsigned short*)p; p += (size_t)CDIM * CDIM * 2;
  unsigned short* wpb = (unsigned short*)p; p += (size_t)CDIM * CDIM * 2;
  const size_t bn = (size_t)NSP * CDIM;  // 2M elements per batch
  unsigned short* hnt = (unsigned short*)p; p += NB * bn * 2;   // also reused as ot
  unsigned short* qt  = (unsigned short*)p; p += NB * bn * 2;
  unsigned short* kt  = (unsigned short*)p; p += NB * bn * 2;
  unsigned short* vcn = (unsigned short*)p; p += NB * bn * 2;
  unsigned short* P   = (unsigned short*)p; p += (size_t)NB * NSP * NSP * 2;  // 128 MiB
  _Float16* Op = (_Float16*)p;  p += (size_t)2 * NB * bn * 2;   // 32 MiB (2 splits)
  float* lsum  = (float*)p;     p += (size_t)NB * NSP * 4;      // 64 KiB
  float* stats = (float*)p;     p += 256 * 4;
  unsigned short* ot = hnt;  // hnt dead after the QKV projections

  hipMemsetAsync(lsum, 0, (size_t)NB * NSP * 4, stream);
  weights_to_bf16<<<dim3(256, 4), 256, 0, stream>>>(wq, wk, wv, wp, wqb, wkb, wvb, wpb);
  gn_stats<<<128, 256, 0, stream>>>(hs, stats);
  norm_transpose<<<dim3(64, 8, 4), 256, 0, stream>>>(hs, stats, gns, gnb, hnt);

  const long sBN = (long)bn;
  const long sPP = (long)NSP * NSP;
  // Fused: Qt[b] = Hnt[b] @ Wq^T + bq ; Kt[b] = Hnt[b] @ Wk^T + bk (z=0..7)
  gemm_nt<2, 1, 0, 1><<<dim3(4, 32, 2 * NB), 256, 0, stream>>>(
      hnt, wqb, qt, bq, nullptr, wkb, kt, bk, NSP, CDIM, CDIM, 1.f, sBN, 0, sBN, 0);
  // Vcn[b] (512x4096) = Wv @ Hnt[b]^T + bv (per-row)
  gemm_nt<1, 1, 0, 0><<<dim3(32, 4, NB), 256, 0, stream>>>(
      wvb, hnt, vcn, bv, nullptr, nullptr, nullptr, nullptr,
      CDIM, NSP, CDIM, 1.f, 0, sBN, sBN, 0);

  // P[b] (4096x4096 bf16) = exp(Qt Kt^T * C^-0.5 - M0); lsum[b][i] += row sums
  const float sc = 0.044194173824159216f;  // 512^-0.5
  gemm256wb<1, 0, 1><<<dim3(16, 16, NB), 1024, 0, stream>>>(
      qt, kt, P, lsum, NSP, NSP, CDIM, sc, sBN, sBN, sPP, 0);

  // PV split-K=2: Op[z] (4096x512 fp16) = P[b][:, ks:+2048] @ Vcn[b][:, same]^T
  gemm256wb<2, 1, 0><<<dim3(2, 16, 2 * NB), 1024, 0, stream>>>(
      P, vcn, Op, nullptr, NSP, CDIM, NSP, 1.f, sPP, sBN, 0, NSP / 2);

  // ot (bf16) = (Op0 + Op1) / lsum
  reduce_div<<<4096, 256, 0, stream>>>(Op, lsum, ot);

  // out[b] (512x4096 fp32) = Wp @ Ot[b]^T + bp (per-row) + residual
  gemm_nt<1, 0, 1, 0><<<dim3(32, 4, NB), 256, 0, stream>>>(
      wpb, ot, (float*)d_out, bp, hs, nullptr, nullptr, nullptr,
      CDIM, NSP, CDIM, 1.f, 0, sBN, sBN, sBN);
}

// Round 16
// 305.075 us; speedup vs baseline: 1.4733x; 1.4733x over previous
//
#include <hip/hip_runtime.h>
#include <cstdint>
#include <cstddef>

// AttnBlock: B=4, C=512, H=W=64 (N=4096). All-fp32 I/O, bf16 MFMA internally.
// R16: exact R12 revert (best known: 297 us; 256x256/BK=64, 16 free-running
//      64x64 waves, counted vmcnt(4), 2 barriers/tile) + T5 s_setprio around
//      the MFMA clusters (free-running waves = role diversity, the documented
//      precondition) + R13/R14's proven fused-QK projection.

#define CDIM 512
#define NSP  4096
#define NB   4
#define M0   12.0f

using bf16x8 = __attribute__((ext_vector_type(8))) __bf16;
using f32x4  = __attribute__((ext_vector_type(4))) float;
using u16x4  = __attribute__((ext_vector_type(4))) unsigned short;
using h8     = __attribute__((ext_vector_type(8))) _Float16;

__device__ __forceinline__ unsigned short f2bf(float f) {
  unsigned int u = __float_as_uint(f);
  u += 0x7fffu + ((u >> 16) & 1u);
  return (unsigned short)(u >> 16);
}

__device__ __forceinline__ void async_copy16(const unsigned short* g, unsigned short* l) {
  __builtin_amdgcn_global_load_lds(
      (const __attribute__((address_space(1))) void*)g,
      (__attribute__((address_space(3))) void*)l, 16, 0, 0);
}

// ---------------- GroupNorm stats: one block per (b, group) ----------------
__global__ __launch_bounds__(256) void gn_stats(const float* __restrict__ x,
                                                float* __restrict__ stats) {
  const size_t base = (size_t)blockIdx.x * 65536;  // 16 ch * 4096, contiguous
  const float4* p = (const float4*)(x + base);
  float s = 0.f, ss = 0.f;
  for (int i = threadIdx.x; i < 16384; i += 256) {
    float4 v = p[i];
    s  += v.x + v.y + v.z + v.w;
    ss += v.x*v.x + v.y*v.y + v.z*v.z + v.w*v.w;
  }
  for (int off = 32; off; off >>= 1) {
    s  += __shfl_xor(s, off);
    ss += __shfl_xor(ss, off);
  }
  __shared__ float rs[4], rss[4];
  const int w = threadIdx.x >> 6;
  if ((threadIdx.x & 63) == 0) { rs[w] = s; rss[w] = ss; }
  __syncthreads();
  if (threadIdx.x == 0) {
    float S  = rs[0] + rs[1] + rs[2] + rs[3];
    float SS = rss[0] + rss[1] + rss[2] + rss[3];
    float mean = S * (1.f / 65536.f);
    float var  = SS * (1.f / 65536.f) - mean * mean;
    stats[2 * blockIdx.x]     = mean;
    stats[2 * blockIdx.x + 1] = rsqrtf(var + 1e-6f);
  }
}

// ------------- normalize + transpose: x(B,C,N) f32 -> Hnt(B,N,C) bf16 -------
__global__ __launch_bounds__(256) void norm_transpose(
    const float* __restrict__ x, const float* __restrict__ stats,
    const float* __restrict__ gns, const float* __restrict__ gnb,
    unsigned short* __restrict__ hnt) {
  __shared__ float tile[64][65];
  const int b  = blockIdx.z;
  const int c0 = blockIdx.y * 64, n0 = blockIdx.x * 64;
  const int tx = threadIdx.x & 63, ty = threadIdx.x >> 6;
  for (int i = 0; i < 16; ++i) {
    int cl = ty * 16 + i;
    int c  = c0 + cl;
    int g  = c >> 4;
    float mean = stats[(b * 32 + g) * 2];
    float rstd = stats[(b * 32 + g) * 2 + 1];
    float v = x[((size_t)(b * CDIM + c)) * NSP + n0 + tx];
    tile[cl][tx] = (v - mean) * rstd * gns[c] + gnb[c];
  }
  __syncthreads();
  for (int i = 0; i < 16; ++i) {
    int nl = ty * 16 + i;
    hnt[((size_t)(b * NSP + n0 + nl)) * CDIM + c0 + tx] = f2bf(tile[tx][nl]);
  }
}

// ---------------- fp32 -> bf16 weight conversion (4 weights, one launch) ----
__global__ __launch_bounds__(256) void weights_to_bf16(
    const float* __restrict__ w0, const float* __restrict__ w1,
    const float* __restrict__ w2, const float* __restrict__ w3,
    unsigned short* __restrict__ o0, unsigned short* __restrict__ o1,
    unsigned short* __restrict__ o2, unsigned short* __restrict__ o3) {
  const float* s; unsigned short* o;
  switch (blockIdx.y) {
    case 0: s = w0; o = o0; break;
    case 1: s = w1; o = o1; break;
    case 2: s = w2; o = o2; break;
    default: s = w3; o = o3; break;
  }
  int i = blockIdx.x * 256 + threadIdx.x;
  float4 v = ((const float4*)s)[i];
  u16x4 r = {f2bf(v.x), f2bf(v.y), f2bf(v.z), f2bf(v.w)};
  *(u16x4*)(o + (size_t)i * 4) = r;
}

// ---------------- NT GEMM 128x128 (R4-proven, small projections) ----------
// FUSEQK: blockIdx.z = sel*4 + b; sel picks (Bt,Dv,bias) vs (Bt2,Dv2,bias2).
template <int BIAS_MODE, int OUT_MODE, int RESID, int FUSEQK>
__global__ __launch_bounds__(256) void gemm_nt(
    const unsigned short* __restrict__ A, const unsigned short* __restrict__ Bt,
    void* __restrict__ Dv, const float* __restrict__ bias,
    const float* __restrict__ resid,
    const unsigned short* __restrict__ Bt2, void* __restrict__ Dv2,
    const float* __restrict__ bias2,
    int M, int N, int K, float scale, long sA, long sB, long sD, long sR) {
  __shared__ unsigned short lsA[2][128 * 32];
  __shared__ unsigned short lsB[2][128 * 32];
  const int tid = threadIdx.x;
  const int w = tid >> 6, lane = tid & 63;
  const int wr = w >> 1, wc = w & 1;
  const int b = FUSEQK ? (blockIdx.z & 3) : blockIdx.z;
  if (FUSEQK && (blockIdx.z >> 2)) { Bt = Bt2; Dv = Dv2; bias = bias2; }
  const int bm0 = blockIdx.y * 128, bn0 = blockIdx.x * 128;
  const unsigned short* Ab = A + (size_t)b * sA;
  const unsigned short* Bb = Bt + (size_t)b * sB;

  f32x4 acc[4][4] = {};
  const int r0  = w * 16 + (lane >> 2);
  const int kof = (lane & 3) * 8;
  const int fr  = lane & 15, kf = (lane >> 4) * 8;

  for (int it = 0; it < 2; ++it) {
    int row = it * 64 + r0;
    async_copy16(Ab + (size_t)(bm0 + row) * K + kof, &lsA[0][row * 32 + kof]);
    async_copy16(Bb + (size_t)(bn0 + row) * K + kof, &lsB[0][row * 32 + kof]);
  }
  __syncthreads();

  int cur = 0;
  for (int k0 = 0; k0 < K; k0 += 32) {
    const int nk = k0 + 32;
    if (nk < K) {
      for (int it = 0; it < 2; ++it) {
        int row = it * 64 + r0;
        async_copy16(Ab + (size_t)(bm0 + row) * K + nk + kof, &lsA[cur ^ 1][row * 32 + kof]);
        async_copy16(Bb + (size_t)(bn0 + row) * K + nk + kof, &lsB[cur ^ 1][row * 32 + kof]);
      }
    }
    bf16x8 af[4], bff[4];
    for (int i = 0; i < 4; ++i) {
      af[i]  = *(const bf16x8*)(&lsA[cur][(wr * 64 + i * 16 + fr) * 32 + kf]);
      bff[i] = *(const bf16x8*)(&lsB[cur][(wc * 64 + i * 16 + fr) * 32 + kf]);
    }
    for (int i = 0; i < 4; ++i)
      for (int j = 0; j < 4; ++j)
        acc[i][j] = __builtin_amdgcn_mfma_f32_16x16x32_bf16(af[i], bff[j], acc[i][j], 0, 0, 0);
    __syncthreads();
    cur ^= 1;
  }

  const int col_l = lane & 15, row_l = (lane >> 4) * 4;
  for (int i = 0; i < 4; ++i)
    for (int j = 0; j < 4; ++j) {
      int gr = bm0 + wr * 64 + i * 16 + row_l;
      int gc = bn0 + wc * 64 + j * 16 + col_l;
      for (int r = 0; r < 4; ++r) {
        float v = acc[i][j][r] * scale;
        if (BIAS_MODE == 1) v += bias[gr + r];
        if (BIAS_MODE == 2) v += bias[gc];
        if (RESID) v += resid[(size_t)b * sR + (size_t)(gr + r) * N + gc];
        if (OUT_MODE == 1)
          ((unsigned short*)Dv)[(size_t)b * sD + (size_t)(gr + r) * N + gc] = f2bf(v);
        else
          ((float*)Dv)[(size_t)b * sD + (size_t)(gr + r) * N + gc] = v;
      }
    }
}

// ------- NT GEMM 256x256, BK=64, 16 free-running waves (1024 thr) -------
// R12 structure (best known) + T5 setprio around the MFMA clusters.
// Per K-tile: [stage next tile (4 loads/thr) -> vmcnt(4) -> barrier ->
// reads + 32 MFMA free-run (kh-sliced) -> barrier]. Reads chunk^(row&7)
// swizzled (source pre-XOR'd, LDS dest linear).
template <int OUT_MODE, int SPLITK, int EXPL>
__global__ __launch_bounds__(1024, 4) void gemm256w(
    const unsigned short* __restrict__ A, const unsigned short* __restrict__ Bt,
    void* __restrict__ Dv, float* __restrict__ lsum,
    int M, int N, int K, float scale, long sA, long sB, long sD, int kLen) {
  __shared__ unsigned short lsA[2][256 * 64];
  __shared__ unsigned short lsB[2][256 * 64];
  const int tid = threadIdx.x;
  const int wid = tid >> 6, lane = tid & 63;
  const int wm = wid >> 2, wn = wid & 3;      // 4 x 4 wave grid, 64x64 each
  const int fr = lane & 15, kq = lane >> 4;
  const int b = SPLITK ? (blockIdx.z & 3) : blockIdx.z;
  const int bm0 = blockIdx.y * 256, bn0 = blockIdx.x * 256;
  const unsigned short* Ab = A + (size_t)b * sA;
  const unsigned short* Bb = Bt + (size_t)b * sB;
  const size_t dOff = SPLITK ? (size_t)blockIdx.z * (size_t)M * N
                             : (size_t)b * (size_t)sD;
  const int kStart = SPLITK ? (blockIdx.z >> 2) * kLen : 0;
  const int ntiles = (SPLITK ? kLen : K) >> 6;

  // stage K-tile t (A,B: 256 rows x 64 k) into buf: 4 loads/thread.
  auto stage = [&](int t, int buf) {
    const int k0 = kStart + t * 64;
#pragma unroll
    for (int i = 0; i < 2; ++i) {
      const int idx = i * 1024 + tid;          // 0..2047 over 256 rows x 8 chunks
      const int row = idx >> 3, ch = idx & 7;
      const int sch = ch ^ (row & 7);
      async_copy16(Ab + (size_t)(bm0 + row) * K + k0 + sch * 8,
                   &lsA[buf][row * 64 + ch * 8]);
    }
#pragma unroll
    for (int i = 0; i < 2; ++i) {
      const int idx = i * 1024 + tid;
      const int row = idx >> 3, ch = idx & 7;
      const int sch = ch ^ (row & 7);
      async_copy16(Bb + (size_t)(bn0 + row) * K + k0 + sch * 8,
                   &lsB[buf][row * 64 + ch * 8]);
    }
  };

  f32x4 acc[4][4] = {};
  const int arow = wm * 64 + fr;
  const int brow = wn * 64 + fr;

  stage(0, 0);
  for (int t = 0; t < ntiles; ++t) {
    const int cur = t & 1;
    if (t + 1 < ntiles) {
      stage(t + 1, cur ^ 1);
      asm volatile("s_waitcnt vmcnt(4)\n\ts_barrier" ::: "memory");
    } else {
      asm volatile("s_waitcnt vmcnt(0)\n\ts_barrier" ::: "memory");
    }
    const unsigned short* la = &lsA[cur][0];
    const unsigned short* lb = &lsB[cur][0];
    // kh-sliced: only 8 frags live at a time (keeps regs <= 128/wave)
#pragma unroll
    for (int kh = 0; kh < 2; ++kh) {
      const int cko = ((kh * 4 + kq) ^ (fr & 7)) * 8;
      bf16x8 af[4], bg[4];
#pragma unroll
      for (int i = 0; i < 4; ++i)
        af[i] = *(const bf16x8*)&la[(arow + i * 16) * 64 + cko];
#pragma unroll
      for (int j = 0; j < 4; ++j)
        bg[j] = *(const bf16x8*)&lb[(brow + j * 16) * 64 + cko];
      __builtin_amdgcn_s_setprio(1);           // T5: favor MFMA-entering wave
#pragma unroll
      for (int i = 0; i < 4; ++i)
#pragma unroll
        for (int j = 0; j < 4; ++j)
          acc[i][j] = __builtin_amdgcn_mfma_f32_16x16x32_bf16(af[i], bg[j], acc[i][j], 0, 0, 0);
      __builtin_amdgcn_s_setprio(0);
    }
    asm volatile("s_barrier" ::: "memory");
  }

  // epilogue
  float rs[4][4];
  if (EXPL)
#pragma unroll
    for (int i = 0; i < 4; ++i)
#pragma unroll
      for (int r = 0; r < 4; ++r) rs[i][r] = 0.f;

#pragma unroll
  for (int mi = 0; mi < 4; ++mi)
#pragma unroll
    for (int ni = 0; ni < 4; ++ni) {
      const int gr = bm0 + wm * 64 + mi * 16 + kq * 4;
      const int gc = bn0 + wn * 64 + ni * 16 + fr;
#pragma unroll
      for (int r = 0; r < 4; ++r) {
        float v;
        if (EXPL) {
          v = __expf(fmaf(acc[mi][ni][r], scale, -M0));
          rs[mi][r] += v;
        } else {
          v = acc[mi][ni][r] * scale;
        }
        if (OUT_MODE == 1)
          ((unsigned short*)Dv)[dOff + (size_t)(gr + r) * N + gc] = f2bf(v);
        else
          ((_Float16*)Dv)[dOff + (size_t)(gr + r) * N + gc] = (_Float16)v;
      }
    }

  if (EXPL) {
#pragma unroll
    for (int mi = 0; mi < 4; ++mi)
#pragma unroll
      for (int r = 0; r < 4; ++r) {
        float v = rs[mi][r];
        v += __shfl_xor(v, 1); v += __shfl_xor(v, 2);
        v += __shfl_xor(v, 4); v += __shfl_xor(v, 8);
        if (fr == 0) {
          int gr = bm0 + wm * 64 + mi * 16 + kq * 4 + r;
          atomicAdd(&lsum[(size_t)b * M + gr], v);
        }
      }
  }
}

// ---------------- reduce: ot = (Op0 + Op1) / l  -> bf16 ----------------
__global__ __launch_bounds__(256) void reduce_div(const _Float16* __restrict__ Op,
                                                  const float* __restrict__ l,
                                                  unsigned short* __restrict__ ot) {
  const size_t stride = (size_t)NB * NSP * CDIM;  // elems per split
  size_t base = ((size_t)blockIdx.x * 256 + threadIdx.x) * 8;
  float linv = 1.f / l[base >> 9];  // row = base / 512
  h8 a = *(const h8*)(Op + base);
  h8 c = *(const h8*)(Op + stride + base);
  u16x4 o0, o1;
#pragma unroll
  for (int i = 0; i < 4; ++i) {
    o0[i] = f2bf(((float)a[i] + (float)c[i]) * linv);
    o1[i] = f2bf(((float)a[i + 4] + (float)c[i + 4]) * linv);
  }
  *(u16x4*)(ot + base) = o0;
  *(u16x4*)(ot + base + 4) = o1;
}

extern "C" void kernel_launch(void* const* d_in, const int* in_sizes, int n_in,
                              void* d_out, int out_size, void* d_ws, size_t ws_size,
                              hipStream_t stream) {
  const float* hs  = (const float*)d_in[0];
  const float* gns = (const float*)d_in[1];
  const float* gnb = (const float*)d_in[2];
  const float* wq  = (const float*)d_in[3];
  const float* bq  = (const float*)d_in[4];
  const float* wk  = (const float*)d_in[5];
  const float* bk  = (const float*)d_in[6];
  const float* wv  = (const float*)d_in[7];
  const float* bv  = (const float*)d_in[8];
  const float* wp  = (const float*)d_in[9];
  const float* bp  = (const float*)d_in[10];

  char* p = (char*)d_ws;
  unsigned short* wqb = (unsigned short*)p; p += (size_t)CDIM * CDIM * 2;
  unsigned short* wkb = (unsigned short*)p; p += (size_t)CDIM * CDIM * 2;
  unsigned short* wvb = (unsigned short*)p; p += (size_t)CDIM * CDIM * 2;
  unsigned short* wpb = (unsigned short*)p; p += (size_t)CDIM * CDIM * 2;
  const size_t bn = (size_t)NSP * CDIM;  // 2M elements per batch
  unsigned short* hnt = (unsigned short*)p; p += NB * bn * 2;   // also reused as ot
  unsigned short* qt  = (unsigned short*)p; p += NB * bn * 2;
  unsigned short* kt  = (unsigned short*)p; p += NB * bn * 2;
  unsigned short* vcn = (unsigned short*)p; p += NB * bn * 2;
  unsigned short* P   = (unsigned short*)p; p += (size_t)NB * NSP * NSP * 2;  // 128 MiB
  _Float16* Op = (_Float16*)p;  p += (size_t)2 * NB * bn * 2;   // 32 MiB (2 splits)
  float* lsum  = (float*)p;     p += (size_t)NB * NSP * 4;      // 64 KiB
  float* stats = (float*)p;     p += 256 * 4;
  unsigned short* ot = hnt;  // hnt dead after the QKV projections

  hipMemsetAsync(lsum, 0, (size_t)NB * NSP * 4, stream);
  weights_to_bf16<<<dim3(256, 4), 256, 0, stream>>>(wq, wk, wv, wp, wqb, wkb, wvb, wpb);
  gn_stats<<<128, 256, 0, stream>>>(hs, stats);
  norm_transpose<<<dim3(64, 8, 4), 256, 0, stream>>>(hs, stats, gns, gnb, hnt);

  const long sBN = (long)bn;
  const long sPP = (long)NSP * NSP;
  // Fused: Qt[b] = Hnt[b] @ Wq^T + bq ; Kt[b] = Hnt[b] @ Wk^T + bk (z=0..7)
  gemm_nt<2, 1, 0, 1><<<dim3(4, 32, 2 * NB), 256, 0, stream>>>(
      hnt, wqb, qt, bq, nullptr, wkb, kt, bk, NSP, CDIM, CDIM, 1.f, sBN, 0, sBN, 0);
  // Vcn[b] (512x4096) = Wv @ Hnt[b]^T + bv (per-row)
  gemm_nt<1, 1, 0, 0><<<dim3(32, 4, NB), 256, 0, stream>>>(
      wvb, hnt, vcn, bv, nullptr, nullptr, nullptr, nullptr,
      CDIM, NSP, CDIM, 1.f, 0, sBN, sBN, 0);

  // P[b] (4096x4096 bf16) = exp(Qt Kt^T * C^-0.5 - M0); lsum[b][i] += row sums
  const float sc = 0.044194173824159216f;  // 512^-0.5
  gemm256w<1, 0, 1><<<dim3(16, 16, NB), 1024, 0, stream>>>(
      qt, kt, P, lsum, NSP, NSP, CDIM, sc, sBN, sBN, sPP, 0);

  // PV split-K=2: Op[z] (4096x512 fp16) = P[b][:, ks:+2048] @ Vcn[b][:, same]^T
  gemm256w<2, 1, 0><<<dim3(2, 16, 2 * NB), 1024, 0, stream>>>(
      P, vcn, Op, nullptr, NSP, CDIM, NSP, 1.f, sPP, sBN, 0, NSP / 2);

  // ot (bf16) = (Op0 + Op1) / lsum
  reduce_div<<<4096, 256, 0, stream>>>(Op, lsum, ot);

  // out[b] (512x4096 fp32) = Wp @ Ot[b]^T + bp (per-row) + residual
  gemm_nt<1, 0, 1, 0><<<dim3(32, 4, NB), 256, 0, stream>>>(
      wpb, ot, (float*)d_out, bp, hs, nullptr, nullptr, nullptr,
      CDIM, NSP, CDIM, 1.f, 0, sBN, sBN, sBN);
}

// Round 17
// 297.425 us; speedup vs baseline: 1.5112x; 1.0257x over previous
//
#include <hip/hip_runtime.h>
#include <cstdint>
#include <cstddef>

// AttnBlock: B=4, C=512, H=W=64 (N=4096). All-fp32 I/O, bf16 MFMA internally.
// R17 (final consolidation): exact R12 gemm256w (best known, 297 us) with
//      NO setprio (R16 showed it costs ~3% here), + fused-QK projection.
//      Pipeline: GN stats -> norm+transpose -> QKV proj -> QK^T+exp (fixed
//      offset, no row max) -> split-K PV -> reduce/l -> proj+residual.

#define CDIM 512
#define NSP  4096
#define NB   4
#define M0   12.0f

using bf16x8 = __attribute__((ext_vector_type(8))) __bf16;
using f32x4  = __attribute__((ext_vector_type(4))) float;
using u16x4  = __attribute__((ext_vector_type(4))) unsigned short;
using h8     = __attribute__((ext_vector_type(8))) _Float16;

__device__ __forceinline__ unsigned short f2bf(float f) {
  unsigned int u = __float_as_uint(f);
  u += 0x7fffu + ((u >> 16) & 1u);
  return (unsigned short)(u >> 16);
}

__device__ __forceinline__ void async_copy16(const unsigned short* g, unsigned short* l) {
  __builtin_amdgcn_global_load_lds(
      (const __attribute__((address_space(1))) void*)g,
      (__attribute__((address_space(3))) void*)l, 16, 0, 0);
}

// ---------------- GroupNorm stats: one block per (b, group) ----------------
__global__ __launch_bounds__(256) void gn_stats(const float* __restrict__ x,
                                                float* __restrict__ stats) {
  const size_t base = (size_t)blockIdx.x * 65536;  // 16 ch * 4096, contiguous
  const float4* p = (const float4*)(x + base);
  float s = 0.f, ss = 0.f;
  for (int i = threadIdx.x; i < 16384; i += 256) {
    float4 v = p[i];
    s  += v.x + v.y + v.z + v.w;
    ss += v.x*v.x + v.y*v.y + v.z*v.z + v.w*v.w;
  }
  for (int off = 32; off; off >>= 1) {
    s  += __shfl_xor(s, off);
    ss += __shfl_xor(ss, off);
  }
  __shared__ float rs[4], rss[4];
  const int w = threadIdx.x >> 6;
  if ((threadIdx.x & 63) == 0) { rs[w] = s; rss[w] = ss; }
  __syncthreads();
  if (threadIdx.x == 0) {
    float S  = rs[0] + rs[1] + rs[2] + rs[3];
    float SS = rss[0] + rss[1] + rss[2] + rss[3];
    float mean = S * (1.f / 65536.f);
    float var  = SS * (1.f / 65536.f) - mean * mean;
    stats[2 * blockIdx.x]     = mean;
    stats[2 * blockIdx.x + 1] = rsqrtf(var + 1e-6f);
  }
}

// ------------- normalize + transpose: x(B,C,N) f32 -> Hnt(B,N,C) bf16 -------
__global__ __launch_bounds__(256) void norm_transpose(
    const float* __restrict__ x, const float* __restrict__ stats,
    const float* __restrict__ gns, const float* __restrict__ gnb,
    unsigned short* __restrict__ hnt) {
  __shared__ float tile[64][65];
  const int b  = blockIdx.z;
  const int c0 = blockIdx.y * 64, n0 = blockIdx.x * 64;
  const int tx = threadIdx.x & 63, ty = threadIdx.x >> 6;
  for (int i = 0; i < 16; ++i) {
    int cl = ty * 16 + i;
    int c  = c0 + cl;
    int g  = c >> 4;
    float mean = stats[(b * 32 + g) * 2];
    float rstd = stats[(b * 32 + g) * 2 + 1];
    float v = x[((size_t)(b * CDIM + c)) * NSP + n0 + tx];
    tile[cl][tx] = (v - mean) * rstd * gns[c] + gnb[c];
  }
  __syncthreads();
  for (int i = 0; i < 16; ++i) {
    int nl = ty * 16 + i;
    hnt[((size_t)(b * NSP + n0 + nl)) * CDIM + c0 + tx] = f2bf(tile[tx][nl]);
  }
}

// ---------------- fp32 -> bf16 weight conversion (4 weights, one launch) ----
__global__ __launch_bounds__(256) void weights_to_bf16(
    const float* __restrict__ w0, const float* __restrict__ w1,
    const float* __restrict__ w2, const float* __restrict__ w3,
    unsigned short* __restrict__ o0, unsigned short* __restrict__ o1,
    unsigned short* __restrict__ o2, unsigned short* __restrict__ o3) {
  const float* s; unsigned short* o;
  switch (blockIdx.y) {
    case 0: s = w0; o = o0; break;
    case 1: s = w1; o = o1; break;
    case 2: s = w2; o = o2; break;
    default: s = w3; o = o3; break;
  }
  int i = blockIdx.x * 256 + threadIdx.x;
  float4 v = ((const float4*)s)[i];
  u16x4 r = {f2bf(v.x), f2bf(v.y), f2bf(v.z), f2bf(v.w)};
  *(u16x4*)(o + (size_t)i * 4) = r;
}

// ---------------- NT GEMM 128x128 (R4-proven, small projections) ----------
// FUSEQK: blockIdx.z = sel*4 + b; sel picks (Bt,Dv,bias) vs (Bt2,Dv2,bias2).
template <int BIAS_MODE, int OUT_MODE, int RESID, int FUSEQK>
__global__ __launch_bounds__(256) void gemm_nt(
    const unsigned short* __restrict__ A, const unsigned short* __restrict__ Bt,
    void* __restrict__ Dv, const float* __restrict__ bias,
    const float* __restrict__ resid,
    const unsigned short* __restrict__ Bt2, void* __restrict__ Dv2,
    const float* __restrict__ bias2,
    int M, int N, int K, float scale, long sA, long sB, long sD, long sR) {
  __shared__ unsigned short lsA[2][128 * 32];
  __shared__ unsigned short lsB[2][128 * 32];
  const int tid = threadIdx.x;
  const int w = tid >> 6, lane = tid & 63;
  const int wr = w >> 1, wc = w & 1;
  const int b = FUSEQK ? (blockIdx.z & 3) : blockIdx.z;
  if (FUSEQK && (blockIdx.z >> 2)) { Bt = Bt2; Dv = Dv2; bias = bias2; }
  const int bm0 = blockIdx.y * 128, bn0 = blockIdx.x * 128;
  const unsigned short* Ab = A + (size_t)b * sA;
  const unsigned short* Bb = Bt + (size_t)b * sB;

  f32x4 acc[4][4] = {};
  const int r0  = w * 16 + (lane >> 2);
  const int kof = (lane & 3) * 8;
  const int fr  = lane & 15, kf = (lane >> 4) * 8;

  for (int it = 0; it < 2; ++it) {
    int row = it * 64 + r0;
    async_copy16(Ab + (size_t)(bm0 + row) * K + kof, &lsA[0][row * 32 + kof]);
    async_copy16(Bb + (size_t)(bn0 + row) * K + kof, &lsB[0][row * 32 + kof]);
  }
  __syncthreads();

  int cur = 0;
  for (int k0 = 0; k0 < K; k0 += 32) {
    const int nk = k0 + 32;
    if (nk < K) {
      for (int it = 0; it < 2; ++it) {
        int row = it * 64 + r0;
        async_copy16(Ab + (size_t)(bm0 + row) * K + nk + kof, &lsA[cur ^ 1][row * 32 + kof]);
        async_copy16(Bb + (size_t)(bn0 + row) * K + nk + kof, &lsB[cur ^ 1][row * 32 + kof]);
      }
    }
    bf16x8 af[4], bff[4];
    for (int i = 0; i < 4; ++i) {
      af[i]  = *(const bf16x8*)(&lsA[cur][(wr * 64 + i * 16 + fr) * 32 + kf]);
      bff[i] = *(const bf16x8*)(&lsB[cur][(wc * 64 + i * 16 + fr) * 32 + kf]);
    }
    for (int i = 0; i < 4; ++i)
      for (int j = 0; j < 4; ++j)
        acc[i][j] = __builtin_amdgcn_mfma_f32_16x16x32_bf16(af[i], bff[j], acc[i][j], 0, 0, 0);
    __syncthreads();
    cur ^= 1;
  }

  const int col_l = lane & 15, row_l = (lane >> 4) * 4;
  for (int i = 0; i < 4; ++i)
    for (int j = 0; j < 4; ++j) {
      int gr = bm0 + wr * 64 + i * 16 + row_l;
      int gc = bn0 + wc * 64 + j * 16 + col_l;
      for (int r = 0; r < 4; ++r) {
        float v = acc[i][j][r] * scale;
        if (BIAS_MODE == 1) v += bias[gr + r];
        if (BIAS_MODE == 2) v += bias[gc];
        if (RESID) v += resid[(size_t)b * sR + (size_t)(gr + r) * N + gc];
        if (OUT_MODE == 1)
          ((unsigned short*)Dv)[(size_t)b * sD + (size_t)(gr + r) * N + gc] = f2bf(v);
        else
          ((float*)Dv)[(size_t)b * sD + (size_t)(gr + r) * N + gc] = v;
      }
    }
}

// ------- NT GEMM 256x256, BK=64, 16 free-running waves (1024 thr) -------
// R12 structure exactly (best known). Per K-tile: [stage next tile (4
// loads/thr) -> vmcnt(4) -> barrier -> reads + 32 MFMA free-run (kh-sliced)
// -> barrier]. Reads chunk^(row&7) swizzled (source pre-XOR'd, LDS linear).
template <int OUT_MODE, int SPLITK, int EXPL>
__global__ __launch_bounds__(1024, 4) void gemm256w(
    const unsigned short* __restrict__ A, const unsigned short* __restrict__ Bt,
    void* __restrict__ Dv, float* __restrict__ lsum,
    int M, int N, int K, float scale, long sA, long sB, long sD, int kLen) {
  __shared__ unsigned short lsA[2][256 * 64];
  __shared__ unsigned short lsB[2][256 * 64];
  const int tid = threadIdx.x;
  const int wid = tid >> 6, lane = tid & 63;
  const int wm = wid >> 2, wn = wid & 3;      // 4 x 4 wave grid, 64x64 each
  const int fr = lane & 15, kq = lane >> 4;
  const int b = SPLITK ? (blockIdx.z & 3) : blockIdx.z;
  const int bm0 = blockIdx.y * 256, bn0 = blockIdx.x * 256;
  const unsigned short* Ab = A + (size_t)b * sA;
  const unsigned short* Bb = Bt + (size_t)b * sB;
  const size_t dOff = SPLITK ? (size_t)blockIdx.z * (size_t)M * N
                             : (size_t)b * (size_t)sD;
  const int kStart = SPLITK ? (blockIdx.z >> 2) * kLen : 0;
  const int ntiles = (SPLITK ? kLen : K) >> 6;

  // stage K-tile t (A,B: 256 rows x 64 k) into buf: 4 loads/thread.
  auto stage = [&](int t, int buf) {
    const int k0 = kStart + t * 64;
#pragma unroll
    for (int i = 0; i < 2; ++i) {
      const int idx = i * 1024 + tid;          // 0..2047 over 256 rows x 8 chunks
      const int row = idx >> 3, ch = idx & 7;
      const int sch = ch ^ (row & 7);
      async_copy16(Ab + (size_t)(bm0 + row) * K + k0 + sch * 8,
                   &lsA[buf][row * 64 + ch * 8]);
    }
#pragma unroll
    for (int i = 0; i < 2; ++i) {
      const int idx = i * 1024 + tid;
      const int row = idx >> 3, ch = idx & 7;
      const int sch = ch ^ (row & 7);
      async_copy16(Bb + (size_t)(bn0 + row) * K + k0 + sch * 8,
                   &lsB[buf][row * 64 + ch * 8]);
    }
  };

  f32x4 acc[4][4] = {};
  const int arow = wm * 64 + fr;
  const int brow = wn * 64 + fr;

  stage(0, 0);
  for (int t = 0; t < ntiles; ++t) {
    const int cur = t & 1;
    if (t + 1 < ntiles) {
      stage(t + 1, cur ^ 1);
      asm volatile("s_waitcnt vmcnt(4)\n\ts_barrier" ::: "memory");
    } else {
      asm volatile("s_waitcnt vmcnt(0)\n\ts_barrier" ::: "memory");
    }
    const unsigned short* la = &lsA[cur][0];
    const unsigned short* lb = &lsB[cur][0];
    // kh-sliced: only 8 frags live at a time (keeps regs <= 128/wave)
#pragma unroll
    for (int kh = 0; kh < 2; ++kh) {
      const int cko = ((kh * 4 + kq) ^ (fr & 7)) * 8;
      bf16x8 af[4], bg[4];
#pragma unroll
      for (int i = 0; i < 4; ++i)
        af[i] = *(const bf16x8*)&la[(arow + i * 16) * 64 + cko];
#pragma unroll
      for (int j = 0; j < 4; ++j)
        bg[j] = *(const bf16x8*)&lb[(brow + j * 16) * 64 + cko];
#pragma unroll
      for (int i = 0; i < 4; ++i)
#pragma unroll
        for (int j = 0; j < 4; ++j)
          acc[i][j] = __builtin_amdgcn_mfma_f32_16x16x32_bf16(af[i], bg[j], acc[i][j], 0, 0, 0);
    }
    asm volatile("s_barrier" ::: "memory");
  }

  // epilogue
  float rs[4][4];
  if (EXPL)
#pragma unroll
    for (int i = 0; i < 4; ++i)
#pragma unroll
      for (int r = 0; r < 4; ++r) rs[i][r] = 0.f;

#pragma unroll
  for (int mi = 0; mi < 4; ++mi)
#pragma unroll
    for (int ni = 0; ni < 4; ++ni) {
      const int gr = bm0 + wm * 64 + mi * 16 + kq * 4;
      const int gc = bn0 + wn * 64 + ni * 16 + fr;
#pragma unroll
      for (int r = 0; r < 4; ++r) {
        float v;
        if (EXPL) {
          v = __expf(fmaf(acc[mi][ni][r], scale, -M0));
          rs[mi][r] += v;
        } else {
          v = acc[mi][ni][r] * scale;
        }
        if (OUT_MODE == 1)
          ((unsigned short*)Dv)[dOff + (size_t)(gr + r) * N + gc] = f2bf(v);
        else
          ((_Float16*)Dv)[dOff + (size_t)(gr + r) * N + gc] = (_Float16)v;
      }
    }

  if (EXPL) {
#pragma unroll
    for (int mi = 0; mi < 4; ++mi)
#pragma unroll
      for (int r = 0; r < 4; ++r) {
        float v = rs[mi][r];
        v += __shfl_xor(v, 1); v += __shfl_xor(v, 2);
        v += __shfl_xor(v, 4); v += __shfl_xor(v, 8);
        if (fr == 0) {
          int gr = bm0 + wm * 64 + mi * 16 + kq * 4 + r;
          atomicAdd(&lsum[(size_t)b * M + gr], v);
        }
      }
  }
}

// ---------------- reduce: ot = (Op0 + Op1) / l  -> bf16 ----------------
__global__ __launch_bounds__(256) void reduce_div(const _Float16* __restrict__ Op,
                                                  const float* __restrict__ l,
                                                  unsigned short* __restrict__ ot) {
  const size_t stride = (size_t)NB * NSP * CDIM;  // elems per split
  size_t base = ((size_t)blockIdx.x * 256 + threadIdx.x) * 8;
  float linv = 1.f / l[base >> 9];  // row = base / 512
  h8 a = *(const h8*)(Op + base);
  h8 c = *(const h8*)(Op + stride + base);
  u16x4 o0, o1;
#pragma unroll
  for (int i = 0; i < 4; ++i) {
    o0[i] = f2bf(((float)a[i] + (float)c[i]) * linv);
    o1[i] = f2bf(((float)a[i + 4] + (float)c[i + 4]) * linv);
  }
  *(u16x4*)(ot + base) = o0;
  *(u16x4*)(ot + base + 4) = o1;
}

extern "C" void kernel_launch(void* const* d_in, const int* in_sizes, int n_in,
                              void* d_out, int out_size, void* d_ws, size_t ws_size,
                              hipStream_t stream) {
  const float* hs  = (const float*)d_in[0];
  const float* gns = (const float*)d_in[1];
  const float* gnb = (const float*)d_in[2];
  const float* wq  = (const float*)d_in[3];
  const float* bq  = (const float*)d_in[4];
  const float* wk  = (const float*)d_in[5];
  const float* bk  = (const float*)d_in[6];
  const float* wv  = (const float*)d_in[7];
  const float* bv  = (const float*)d_in[8];
  const float* wp  = (const float*)d_in[9];
  const float* bp  = (const float*)d_in[10];

  char* p = (char*)d_ws;
  unsigned short* wqb = (unsigned short*)p; p += (size_t)CDIM * CDIM * 2;
  unsigned short* wkb = (unsigned short*)p; p += (size_t)CDIM * CDIM * 2;
  unsigned short* wvb = (unsigned short*)p; p += (size_t)CDIM * CDIM * 2;
  unsigned short* wpb = (unsigned short*)p; p += (size_t)CDIM * CDIM * 2;
  const size_t bn = (size_t)NSP * CDIM;  // 2M elements per batch
  unsigned short* hnt = (unsigned short*)p; p += NB * bn * 2;   // also reused as ot
  unsigned short* qt  = (unsigned short*)p; p += NB * bn * 2;
  unsigned short* kt  = (unsigned short*)p; p += NB * bn * 2;
  unsigned short* vcn = (unsigned short*)p; p += NB * bn * 2;
  unsigned short* P   = (unsigned short*)p; p += (size_t)NB * NSP * NSP * 2;  // 128 MiB
  _Float16* Op = (_Float16*)p;  p += (size_t)2 * NB * bn * 2;   // 32 MiB (2 splits)
  float* lsum  = (float*)p;     p += (size_t)NB * NSP * 4;      // 64 KiB
  float* stats = (float*)p;     p += 256 * 4;
  unsigned short* ot = hnt;  // hnt dead after the QKV projections

  hipMemsetAsync(lsum, 0, (size_t)NB * NSP * 4, stream);
  weights_to_bf16<<<dim3(256, 4), 256, 0, stream>>>(wq, wk, wv, wp, wqb, wkb, wvb, wpb);
  gn_stats<<<128, 256, 0, stream>>>(hs, stats);
  norm_transpose<<<dim3(64, 8, 4), 256, 0, stream>>>(hs, stats, gns, gnb, hnt);

  const long sBN = (long)bn;
  const long sPP = (long)NSP * NSP;
  // Fused: Qt[b] = Hnt[b] @ Wq^T + bq ; Kt[b] = Hnt[b] @ Wk^T + bk (z=0..7)
  gemm_nt<2, 1, 0, 1><<<dim3(4, 32, 2 * NB), 256, 0, stream>>>(
      hnt, wqb, qt, bq, nullptr, wkb, kt, bk, NSP, CDIM, CDIM, 1.f, sBN, 0, sBN, 0);
  // Vcn[b] (512x4096) = Wv @ Hnt[b]^T + bv (per-row)
  gemm_nt<1, 1, 0, 0><<<dim3(32, 4, NB), 256, 0, stream>>>(
      wvb, hnt, vcn, bv, nullptr, nullptr, nullptr, nullptr,
      CDIM, NSP, CDIM, 1.f, 0, sBN, sBN, 0);

  // P[b] (4096x4096 bf16) = exp(Qt Kt^T * C^-0.5 - M0); lsum[b][i] += row sums
  const float sc = 0.044194173824159216f;  // 512^-0.5
  gemm256w<1, 0, 1><<<dim3(16, 16, NB), 1024, 0, stream>>>(
      qt, kt, P, lsum, NSP, NSP, CDIM, sc, sBN, sBN, sPP, 0);

  // PV split-K=2: Op[z] (4096x512 fp16) = P[b][:, ks:+2048] @ Vcn[b][:, same]^T
  gemm256w<2, 1, 0><<<dim3(2, 16, 2 * NB), 1024, 0, stream>>>(
      P, vcn, Op, nullptr, NSP, CDIM, NSP, 1.f, sPP, sBN, 0, NSP / 2);

  // ot (bf16) = (Op0 + Op1) / lsum
  reduce_div<<<4096, 256, 0, stream>>>(Op, lsum, ot);

  // out[b] (512x4096 fp32) = Wp @ Ot[b]^T + bp (per-row) + residual
  gemm_nt<1, 0, 1, 0><<<dim3(32, 4, NB), 256, 0, stream>>>(
      wpb, ot, (float*)d_out, bp, hs, nullptr, nullptr, nullptr,
      CDIM, NSP, CDIM, 1.f, 0, sBN, sBN, sBN);
}